// Round 6
// baseline (579.485 us; speedup 1.0000x reference)
//
#include <hip/hip_runtime.h>

// ---------------------------------------------------------------------------
// GATv2 feature extractor, MI355X (gfx950).
// Graphs are 400-node independent blocks; edges are graph-contiguous.
//  - CSR-by-dst built on device each call (counts -> per-graph scan -> scatter).
//    NOTE: harness delivers integer inputs as int32 (edge_index read as int*).
//  - k_transform: lane=node design, LDS-free. Each wave: 64 nodes x 16 cols.
//    W rows read via wave-uniform (readfirstlane-forced) addresses -> s_load;
//    h rows gathered per-lane from global (L2/L3-resident, no reuse anyway).
//  - k_edge: one block (512 thr) per graph; xl tile staged in LDS (stride 68
//    floats -> 4-bank rotation per row). 8-lane groups, 8 channels/lane,
//    DPP-based 8-lane reduce (VALU pipe, no DS shuffles), leaky = fmax(t,.2t),
//    online softmax with branch-free per-4-edge-chunk rescale, CSR indices
//    loaded 4-at-a-time via aligned b64.
// ---------------------------------------------------------------------------

static constexpr int N_NODES = 102400;
static constexpr int N_GRAPH = 256;
static constexpr int NPG     = 400;
static constexpr int EPG     = 6400;
static constexpr int E_IN    = 1638400;
static constexpr int CSTR    = EPG + NPG;     // 6800 CSR slots per graph
static constexpr int E_TOT   = E_IN + N_NODES;
static constexpr int XSTR    = 68;            // padded LDS row stride (floats)

// ---------------- CSR build ----------------

__global__ __launch_bounds__(256)
void k_init(int* __restrict__ cursor, int* __restrict__ off) {
    int i = blockIdx.x * 256 + threadIdx.x;
    if (i < N_NODES) cursor[i] = 1;            // self-loop pre-count
    if (i == 0) off[N_NODES] = E_TOT;
}

__global__ __launch_bounds__(256)
void k_count(const int* __restrict__ ei, int* __restrict__ cursor) {
    int e = blockIdx.x * 256 + threadIdx.x;
    if (e >= E_IN) return;
    unsigned d = (unsigned)ei[E_IN + e];       // int32 input (harness contract)
    if (d < (unsigned)N_NODES) atomicAdd(&cursor[d], 1);
}

__global__ __launch_bounds__(512)
void k_scan(int* __restrict__ cursor, int* __restrict__ off,
            unsigned short* __restrict__ csr) {
    __shared__ int s[512];
    int g = blockIdx.x, t = threadIdx.x;
    int base = g * NPG;
    int cnt = (t < NPG) ? cursor[base + t] : 0;
    s[t] = cnt;
    for (int d = 1; d < 512; d <<= 1) {
        __syncthreads();
        int v = (t >= d) ? s[t - d] : 0;
        __syncthreads();
        s[t] += v;
    }
    __syncthreads();
    if (t < NPG) {
        int o = g * CSTR + (s[t] - cnt);       // exclusive prefix
        off[base + t] = o;
        cursor[base + t] = o + 1;              // slot 0 = self loop
        csr[o] = (unsigned short)t;
    }
}

__global__ __launch_bounds__(256)
void k_scatter(const int* __restrict__ ei, int* __restrict__ cursor,
               unsigned short* __restrict__ csr) {
    int e = blockIdx.x * 256 + threadIdx.x;
    if (e >= E_IN) return;
    unsigned s = (unsigned)ei[e];
    unsigned d = (unsigned)ei[E_IN + e];
    if (d >= (unsigned)N_NODES || s >= (unsigned)N_NODES) return;  // guard
    int pos = atomicAdd(&cursor[d], 1);
    csr[pos] = (unsigned short)(s % NPG);      // src is in dst's graph
}

// ---------------- node transform (LDS-free, lane = node) ----------------
// grid = (N/64)*2 blocks of 256 (4 waves). Block bit0 selects Wl/Wr half.
// Wave = 64 nodes x 16 columns; W via uniform scalar loads; h via per-lane
// global gather (row is this lane's private data; no reuse exists).

#define FMA16(hk, wp) {                                                        \
    float4 w0_ = *(const float4*)&(wp)[0];                                     \
    float4 w1_ = *(const float4*)&(wp)[4];                                     \
    float4 w2_ = *(const float4*)&(wp)[8];                                     \
    float4 w3_ = *(const float4*)&(wp)[12];                                    \
    acc0  += (hk) * w0_.x; acc1  += (hk) * w0_.y;                              \
    acc2  += (hk) * w0_.z; acc3  += (hk) * w0_.w;                              \
    acc4  += (hk) * w1_.x; acc5  += (hk) * w1_.y;                              \
    acc6  += (hk) * w1_.z; acc7  += (hk) * w1_.w;                              \
    acc8  += (hk) * w2_.x; acc9  += (hk) * w2_.y;                              \
    acc10 += (hk) * w2_.z; acc11 += (hk) * w2_.w;                              \
    acc12 += (hk) * w3_.x; acc13 += (hk) * w3_.y;                              \
    acc14 += (hk) * w3_.z; acc15 += (hk) * w3_.w; }

template<int K>
__global__ __launch_bounds__(256)
void k_transform(const float* __restrict__ h, const float* __restrict__ Wl,
                 const float* __restrict__ Wr, const float* __restrict__ bl,
                 const float* __restrict__ br, float* __restrict__ xcat) {
    int bid  = blockIdx.x;
    int half = bid & 1;
    int tid  = threadIdx.x;
    int lane = tid & 63;
    int node = (bid >> 1) * 64 + lane;
    int c0   = __builtin_amdgcn_readfirstlane((tid >> 6) * 16);
    const float* __restrict__ W  = half ? Wr : Wl;
    const float* __restrict__ bb = half ? br : bl;

    float acc0 = 0.f, acc1 = 0.f, acc2 = 0.f, acc3 = 0.f;
    float acc4 = 0.f, acc5 = 0.f, acc6 = 0.f, acc7 = 0.f;
    float acc8 = 0.f, acc9 = 0.f, acc10 = 0.f, acc11 = 0.f;
    float acc12 = 0.f, acc13 = 0.f, acc14 = 0.f, acc15 = 0.f;

    constexpr int KQ = (K + 3) / 4;
    #pragma unroll
    for (int k4 = 0; k4 < KQ; ++k4) {
        float hv0, hv1, hv2, hv3;
        if constexpr ((K & 3) == 0) {
            float4 h4 = *(const float4*)&h[(size_t)node * K + k4 * 4];
            hv0 = h4.x; hv1 = h4.y; hv2 = h4.z; hv3 = h4.w;
        } else {
            const float* hr = &h[(size_t)node * K + k4 * 4];
            hv0 = (k4 * 4 + 0 < K) ? hr[0] : 0.f;
            hv1 = (k4 * 4 + 1 < K) ? hr[1] : 0.f;
            hv2 = (k4 * 4 + 2 < K) ? hr[2] : 0.f;
            hv3 = (k4 * 4 + 3 < K) ? hr[3] : 0.f;
        }
        if (k4 * 4 + 0 < K) FMA16(hv0, &W[(size_t)(k4 * 4 + 0) * 64 + c0]);
        if (k4 * 4 + 1 < K) FMA16(hv1, &W[(size_t)(k4 * 4 + 1) * 64 + c0]);
        if (k4 * 4 + 2 < K) FMA16(hv2, &W[(size_t)(k4 * 4 + 2) * 64 + c0]);
        if (k4 * 4 + 3 < K) FMA16(hv3, &W[(size_t)(k4 * 4 + 3) * 64 + c0]);
    }

    size_t ob = (size_t)node * 128 + half * 64 + c0;
    float4 r0 = {acc0  + bb[c0 + 0],  acc1  + bb[c0 + 1],
                 acc2  + bb[c0 + 2],  acc3  + bb[c0 + 3]};
    float4 r1 = {acc4  + bb[c0 + 4],  acc5  + bb[c0 + 5],
                 acc6  + bb[c0 + 6],  acc7  + bb[c0 + 7]};
    float4 r2 = {acc8  + bb[c0 + 8],  acc9  + bb[c0 + 9],
                 acc10 + bb[c0 + 10], acc11 + bb[c0 + 11]};
    float4 r3 = {acc12 + bb[c0 + 12], acc13 + bb[c0 + 13],
                 acc14 + bb[c0 + 14], acc15 + bb[c0 + 15]};
    *(float4*)&xcat[ob + 0]  = r0;
    *(float4*)&xcat[ob + 4]  = r1;
    *(float4*)&xcat[ob + 8]  = r2;
    *(float4*)&xcat[ob + 12] = r3;
}

// ---------------- edge phase ----------------

// 8-lane-group sum, all lanes get total. VALU-pipe DPP, no DS shuffles.
__device__ __forceinline__ float red8(float x) {
    x += __int_as_float(__builtin_amdgcn_update_dpp(
            0, __float_as_int(x), 0xB1, 0xF, 0xF, true));   // quad xor1
    x += __int_as_float(__builtin_amdgcn_update_dpp(
            0, __float_as_int(x), 0x4E, 0xF, 0xF, true));   // quad xor2
    x += __int_as_float(__builtin_amdgcn_update_dpp(
            0, __float_as_int(x), 0x141, 0xF, 0xF, true));  // row_half_mirror
    return x;
}

__device__ __forceinline__ float pe_of(const float* __restrict__ xl_s, int sl,
                                       int oc, float4 xra, float4 xrb,
                                       float4 ata, float4 atb,
                                       float4& va, float4& vb) {
    va = *(const float4*)&xl_s[sl * XSTR + oc * 8];
    vb = *(const float4*)&xl_s[sl * XSTR + oc * 8 + 4];
    float t, d;
    t = va.x + xra.x; d  = fmaxf(t, 0.2f * t) * ata.x;
    t = va.y + xra.y; d += fmaxf(t, 0.2f * t) * ata.y;
    t = va.z + xra.z; d += fmaxf(t, 0.2f * t) * ata.z;
    t = va.w + xra.w; d += fmaxf(t, 0.2f * t) * ata.w;
    t = vb.x + xrb.x; d += fmaxf(t, 0.2f * t) * atb.x;
    t = vb.y + xrb.y; d += fmaxf(t, 0.2f * t) * atb.y;
    t = vb.z + xrb.z; d += fmaxf(t, 0.2f * t) * atb.z;
    t = vb.w + xrb.w; d += fmaxf(t, 0.2f * t) * atb.w;
    return red8(d);
}

template<int RELU, int FINAL>
__global__ __launch_bounds__(512)
void k_edge(const float* __restrict__ xcat, const unsigned short* __restrict__ csr,
            const int* __restrict__ off, const float* __restrict__ att,
            const float* __restrict__ bias, const int* __restrict__ reach,
            float* __restrict__ out) {
    __shared__ __align__(16) float xl_s[NPG * XSTR];
    __shared__ __align__(8) unsigned short csr_s[CSTR];
    __shared__ unsigned short off_s[404];
    int g = blockIdx.x;
    int gbase = g * NPG;
    int tid = threadIdx.x;

    for (int q = tid; q < NPG * 16; q += 512) {             // xl half, 6400 f4
        int node = q >> 4, c4 = q & 15;
        *(float4*)&xl_s[node * XSTR + c4 * 4] =
            *(const float4*)&xcat[(size_t)(gbase + node) * 128 + c4 * 4];
    }
    const unsigned int* csrg = (const unsigned int*)(csr + (size_t)g * CSTR);
    for (int q = tid; q < CSTR / 2; q += 512)
        ((unsigned int*)csr_s)[q] = csrg[q];
    for (int q = tid; q < NPG + 1; q += 512)
        off_s[q] = (unsigned short)(off[gbase + q] - g * CSTR);
    __syncthreads();

    int grp = tid >> 3;                                     // 64 groups
    int oc  = tid & 7;                                      // channel octant
    float4 ata = *(const float4*)&att[oc * 8];
    float4 atb = *(const float4*)&att[oc * 8 + 4];
    float4 bia = *(const float4*)&bias[oc * 8];
    float4 bib = *(const float4*)&bias[oc * 8 + 4];

    for (int dl = grp; dl < NPG; dl += 64) {
        int node = gbase + dl;
        float4 xra = *(const float4*)&xcat[(size_t)node * 128 + 64 + oc * 8];
        float4 xrb = *(const float4*)&xcat[(size_t)node * 128 + 64 + oc * 8 + 4];
        int beg = off_s[dl], end = off_s[dl + 1];

        float4 aa, ab, va, vb;
        float m = pe_of(xl_s, dl, oc, xra, xrb, ata, atb, va, vb); // self loop
        float dsum = 1.f;
        aa = va; ab = vb;

        int p = beg + 1;
        int pa = (p + 3) & ~3;                 // first 4-aligned slot
        if (pa > end) pa = end;
        for (; p < pa; ++p) {                  // prologue (0..3 edges)
            float4 wa, wb;
            float pe = pe_of(xl_s, csr_s[p], oc, xra, xrb, ata, atb, wa, wb);
            float cm = fmaxf(m, pe);
            float sc = __expf(m - cm);
            float ex = __expf(pe - cm);
            m = cm;
            dsum = dsum * sc + ex;
            aa.x = aa.x * sc + ex * wa.x;  aa.y = aa.y * sc + ex * wa.y;
            aa.z = aa.z * sc + ex * wa.z;  aa.w = aa.w * sc + ex * wa.w;
            ab.x = ab.x * sc + ex * wb.x;  ab.y = ab.y * sc + ex * wb.y;
            ab.z = ab.z * sc + ex * wb.z;  ab.w = ab.w * sc + ex * wb.w;
        }
        for (; p + 4 <= end; p += 4) {         // aligned 4-edge chunks
            unsigned long long iv = *(const unsigned long long*)&csr_s[p];
            int s0 = (int)(iv & 0xFFFF),         s1 = (int)((iv >> 16) & 0xFFFF);
            int s2 = (int)((iv >> 32) & 0xFFFF), s3 = (int)(iv >> 48);
            float4 v0a, v0b, v1a, v1b, v2a, v2b, v3a, v3b;
            float p0 = pe_of(xl_s, s0, oc, xra, xrb, ata, atb, v0a, v0b);
            float p1 = pe_of(xl_s, s1, oc, xra, xrb, ata, atb, v1a, v1b);
            float p2 = pe_of(xl_s, s2, oc, xra, xrb, ata, atb, v2a, v2b);
            float p3 = pe_of(xl_s, s3, oc, xra, xrb, ata, atb, v3a, v3b);
            float cm = fmaxf(fmaxf(fmaxf(p0, p1), fmaxf(p2, p3)), m);
            float sc = __expf(m - cm);          // == 1.0 usually
            m = cm;
            float e0 = __expf(p0 - m), e1 = __expf(p1 - m);
            float e2 = __expf(p2 - m), e3 = __expf(p3 - m);
            dsum = dsum * sc + (e0 + e1) + (e2 + e3);
            aa.x = aa.x * sc + e0 * v0a.x + e1 * v1a.x + e2 * v2a.x + e3 * v3a.x;
            aa.y = aa.y * sc + e0 * v0a.y + e1 * v1a.y + e2 * v2a.y + e3 * v3a.y;
            aa.z = aa.z * sc + e0 * v0a.z + e1 * v1a.z + e2 * v2a.z + e3 * v3a.z;
            aa.w = aa.w * sc + e0 * v0a.w + e1 * v1a.w + e2 * v2a.w + e3 * v3a.w;
            ab.x = ab.x * sc + e0 * v0b.x + e1 * v1b.x + e2 * v2b.x + e3 * v3b.x;
            ab.y = ab.y * sc + e0 * v0b.y + e1 * v1b.y + e2 * v2b.y + e3 * v3b.y;
            ab.z = ab.z * sc + e0 * v0b.z + e1 * v1b.z + e2 * v2b.z + e3 * v3b.z;
            ab.w = ab.w * sc + e0 * v0b.w + e1 * v1b.w + e2 * v2b.w + e3 * v3b.w;
        }
        for (; p < end; ++p) {                 // tail (0..3 edges)
            float4 wa, wb;
            float pe = pe_of(xl_s, csr_s[p], oc, xra, xrb, ata, atb, wa, wb);
            float cm = fmaxf(m, pe);
            float sc = __expf(m - cm);
            float ex = __expf(pe - cm);
            m = cm;
            dsum = dsum * sc + ex;
            aa.x = aa.x * sc + ex * wa.x;  aa.y = aa.y * sc + ex * wa.y;
            aa.z = aa.z * sc + ex * wa.z;  aa.w = aa.w * sc + ex * wa.w;
            ab.x = ab.x * sc + ex * wb.x;  ab.y = ab.y * sc + ex * wb.y;
            ab.z = ab.z * sc + ex * wb.z;  ab.w = ab.w * sc + ex * wb.w;
        }

        float inv = 1.0f / dsum;
        float4 ra = {aa.x * inv + bia.x, aa.y * inv + bia.y,
                     aa.z * inv + bia.z, aa.w * inv + bia.w};
        float4 rb = {ab.x * inv + bib.x, ab.y * inv + bib.y,
                     ab.z * inv + bib.z, ab.w * inv + bib.w};
        if (RELU) {
            ra.x = fmaxf(ra.x, 0.f); ra.y = fmaxf(ra.y, 0.f);
            ra.z = fmaxf(ra.z, 0.f); ra.w = fmaxf(ra.w, 0.f);
            rb.x = fmaxf(rb.x, 0.f); rb.y = fmaxf(rb.y, 0.f);
            rb.z = fmaxf(rb.z, 0.f); rb.w = fmaxf(rb.w, 0.f);
        }
        if (FINAL) {                           // 67-stride rows: scalar stores
            size_t b = (size_t)node * 67 + oc * 8;
            out[b + 0] = ra.x; out[b + 1] = ra.y;
            out[b + 2] = ra.z; out[b + 3] = ra.w;
            out[b + 4] = rb.x; out[b + 5] = rb.y;
            out[b + 6] = rb.z; out[b + 7] = rb.w;
        } else {
            *(float4*)&out[(size_t)node * 64 + oc * 8]     = ra;
            *(float4*)&out[(size_t)node * 64 + oc * 8 + 4] = rb;
        }
    }

    if (FINAL) {                               // trailing 3 feature columns
        if (tid < NPG) {
            int node = gbase + tid;
            float dec = (float)(g & 63);
            float nn  = ((g & 63) == 0 && tid < 256) ? 400.f : 0.f;
            size_t b = (size_t)node * 67;
            out[b + 64] = dec;
            out[b + 65] = (float)reach[node];
            out[b + 66] = nn;
        }
    }
}

// ---------------- launch ----------------

extern "C" void kernel_launch(void* const* d_in, const int* in_sizes, int n_in,
                              void* d_out, int out_size, void* d_ws, size_t ws_size,
                              hipStream_t stream) {
    const float* x     = (const float*)d_in[0];
    const int*   ei    = (const int*)d_in[1];     // int32 per harness contract
    const int*   reach = (const int*)d_in[2];
    const float* Wl0   = (const float*)d_in[3];
    const float* Wr0   = (const float*)d_in[4];
    const float* bl0   = (const float*)d_in[5];
    const float* br0   = (const float*)d_in[6];
    const float* att0  = (const float*)d_in[7];
    const float* bias0 = (const float*)d_in[8];
    const float* Wl    = (const float*)d_in[9];
    const float* Wr    = (const float*)d_in[10];
    const float* bl    = (const float*)d_in[11];
    const float* br    = (const float*)d_in[12];
    const float* att   = (const float*)d_in[13];
    const float* bias  = (const float*)d_in[14];
    float* out = (float*)d_out;

    // workspace: h (26.2 MB) | xcat (52.4 MB) | csr (3.5 MB) | off | cursor
    char* ws = (char*)d_ws;
    float* h    = (float*)ws;  ws += (size_t)N_NODES * 64 * 4;
    float* xcat = (float*)ws;  ws += (size_t)N_NODES * 128 * 4;
    unsigned short* csr = (unsigned short*)ws;  ws += (size_t)E_TOT * 2;
    int* off    = (int*)ws;    ws += (size_t)(N_NODES + 1) * 4;
    int* cursor = (int*)ws;

    k_init   <<<(N_NODES + 255) / 256, 256, 0, stream>>>(cursor, off);
    k_count  <<<(E_IN + 255) / 256, 256, 0, stream>>>(ei, cursor);
    k_scan   <<<N_GRAPH, 512, 0, stream>>>(cursor, off, csr);
    k_scatter<<<(E_IN + 255) / 256, 256, 0, stream>>>(ei, cursor, csr);

    k_transform<7><<<N_NODES / 64 * 2, 256, 0, stream>>>(
        x, Wl0, Wr0, bl0, br0, xcat);
    k_edge<1, 0><<<N_GRAPH, 512, 0, stream>>>(xcat, csr, off, att0, bias0,
                                              reach, h);

    for (int i = 0; i < 4; ++i) {
        k_transform<64><<<N_NODES / 64 * 2, 256, 0, stream>>>(
            h, Wl + i * 4096, Wr + i * 4096, bl + i * 64, br + i * 64, xcat);
        if (i < 3) {
            k_edge<1, 0><<<N_GRAPH, 512, 0, stream>>>(
                xcat, csr, off, att + i * 64, bias + i * 64, reach, h);
        } else {
            k_edge<0, 1><<<N_GRAPH, 512, 0, stream>>>(
                xcat, csr, off, att + i * 64, bias + i * 64, reach, out);
        }
    }
}

// Round 9
// 559.679 us; speedup vs baseline: 1.0354x; 1.0354x over previous
//
#include <hip/hip_runtime.h>

// ---------------------------------------------------------------------------
// GATv2 feature extractor, MI355X (gfx950).
// Graphs are 400-node independent blocks; edges are graph-contiguous.
//  - CSR-by-dst built on device each call (counts -> per-graph scan -> scatter).
//    NOTE: harness delivers integer inputs as int32 (edge_index read as int*).
//  - k_transform: lane=node design, LDS-free. Each wave: 64 nodes x 16 cols.
//    W rows read via wave-uniform (readfirstlane-forced) addresses -> s_load;
//    h rows gathered per-lane from global (L2/L3-resident, no reuse anyway).
//  - k_edge: one block (1024 thr = 16 waves) per graph; xl tile staged in LDS
//    (stride 68 floats -> 4-bank rotation per row). LDS 120.5 KiB allows only
//    1 block/CU, so block size 1024 (not 512) doubles waves/SIMD to 4 for
//    latency hiding (R6 profile: 512-thr had Occupancy 15.6%, VALUBusy 55%).
//    8-lane groups, 8 channels/lane, DPP-based 8-lane reduce (VALU pipe),
//    leaky = fmax(t,.2t), online softmax with branch-free per-4-edge-chunk
//    rescale, CSR indices loaded 4-at-a-time via aligned b64.
// ---------------------------------------------------------------------------

static constexpr int N_NODES = 102400;
static constexpr int N_GRAPH = 256;
static constexpr int NPG     = 400;
static constexpr int EPG     = 6400;
static constexpr int E_IN    = 1638400;
static constexpr int CSTR    = EPG + NPG;     // 6800 CSR slots per graph
static constexpr int E_TOT   = E_IN + N_NODES;
static constexpr int XSTR    = 68;            // padded LDS row stride (floats)
static constexpr int EBLK    = 1024;          // k_edge block size (16 waves)

// ---------------- CSR build ----------------

__global__ __launch_bounds__(256)
void k_init(int* __restrict__ cursor, int* __restrict__ off) {
    int i = blockIdx.x * 256 + threadIdx.x;
    if (i < N_NODES) cursor[i] = 1;            // self-loop pre-count
    if (i == 0) off[N_NODES] = E_TOT;
}

__global__ __launch_bounds__(256)
void k_count(const int* __restrict__ ei, int* __restrict__ cursor) {
    int e = blockIdx.x * 256 + threadIdx.x;
    if (e >= E_IN) return;
    unsigned d = (unsigned)ei[E_IN + e];       // int32 input (harness contract)
    if (d < (unsigned)N_NODES) atomicAdd(&cursor[d], 1);
}

__global__ __launch_bounds__(512)
void k_scan(int* __restrict__ cursor, int* __restrict__ off,
            unsigned short* __restrict__ csr) {
    __shared__ int s[512];
    int g = blockIdx.x, t = threadIdx.x;
    int base = g * NPG;
    int cnt = (t < NPG) ? cursor[base + t] : 0;
    s[t] = cnt;
    for (int d = 1; d < 512; d <<= 1) {
        __syncthreads();
        int v = (t >= d) ? s[t - d] : 0;
        __syncthreads();
        s[t] += v;
    }
    __syncthreads();
    if (t < NPG) {
        int o = g * CSTR + (s[t] - cnt);       // exclusive prefix
        off[base + t] = o;
        cursor[base + t] = o + 1;              // slot 0 = self loop
        csr[o] = (unsigned short)t;
    }
}

__global__ __launch_bounds__(256)
void k_scatter(const int* __restrict__ ei, int* __restrict__ cursor,
               unsigned short* __restrict__ csr) {
    int e = blockIdx.x * 256 + threadIdx.x;
    if (e >= E_IN) return;
    unsigned s = (unsigned)ei[e];
    unsigned d = (unsigned)ei[E_IN + e];
    if (d >= (unsigned)N_NODES || s >= (unsigned)N_NODES) return;  // guard
    int pos = atomicAdd(&cursor[d], 1);
    csr[pos] = (unsigned short)(s % NPG);      // src is in dst's graph
}

// ---------------- node transform (LDS-free, lane = node) ----------------
// grid = (N/64)*2 blocks of 256 (4 waves). Block bit0 selects Wl/Wr half.
// Wave = 64 nodes x 16 columns; W via uniform scalar loads; h via per-lane
// global gather (row is this lane's private data; no reuse exists).

#define FMA16(hk, wp) {                                                        \
    float4 w0_ = *(const float4*)&(wp)[0];                                     \
    float4 w1_ = *(const float4*)&(wp)[4];                                     \
    float4 w2_ = *(const float4*)&(wp)[8];                                     \
    float4 w3_ = *(const float4*)&(wp)[12];                                    \
    acc0  += (hk) * w0_.x; acc1  += (hk) * w0_.y;                              \
    acc2  += (hk) * w0_.z; acc3  += (hk) * w0_.w;                              \
    acc4  += (hk) * w1_.x; acc5  += (hk) * w1_.y;                              \
    acc6  += (hk) * w1_.z; acc7  += (hk) * w1_.w;                              \
    acc8  += (hk) * w2_.x; acc9  += (hk) * w2_.y;                              \
    acc10 += (hk) * w2_.z; acc11 += (hk) * w2_.w;                              \
    acc12 += (hk) * w3_.x; acc13 += (hk) * w3_.y;                              \
    acc14 += (hk) * w3_.z; acc15 += (hk) * w3_.w; }

template<int K>
__global__ __launch_bounds__(256)
void k_transform(const float* __restrict__ h, const float* __restrict__ Wl,
                 const float* __restrict__ Wr, const float* __restrict__ bl,
                 const float* __restrict__ br, float* __restrict__ xcat) {
    int bid  = blockIdx.x;
    int half = bid & 1;
    int tid  = threadIdx.x;
    int lane = tid & 63;
    int node = (bid >> 1) * 64 + lane;
    int c0   = __builtin_amdgcn_readfirstlane((tid >> 6) * 16);
    const float* __restrict__ W  = half ? Wr : Wl;
    const float* __restrict__ bb = half ? br : bl;

    float acc0 = 0.f, acc1 = 0.f, acc2 = 0.f, acc3 = 0.f;
    float acc4 = 0.f, acc5 = 0.f, acc6 = 0.f, acc7 = 0.f;
    float acc8 = 0.f, acc9 = 0.f, acc10 = 0.f, acc11 = 0.f;
    float acc12 = 0.f, acc13 = 0.f, acc14 = 0.f, acc15 = 0.f;

    constexpr int KQ = (K + 3) / 4;
    #pragma unroll
    for (int k4 = 0; k4 < KQ; ++k4) {
        float hv0, hv1, hv2, hv3;
        if constexpr ((K & 3) == 0) {
            float4 h4 = *(const float4*)&h[(size_t)node * K + k4 * 4];
            hv0 = h4.x; hv1 = h4.y; hv2 = h4.z; hv3 = h4.w;
        } else {
            const float* hr = &h[(size_t)node * K + k4 * 4];
            hv0 = (k4 * 4 + 0 < K) ? hr[0] : 0.f;
            hv1 = (k4 * 4 + 1 < K) ? hr[1] : 0.f;
            hv2 = (k4 * 4 + 2 < K) ? hr[2] : 0.f;
            hv3 = (k4 * 4 + 3 < K) ? hr[3] : 0.f;
        }
        if (k4 * 4 + 0 < K) FMA16(hv0, &W[(size_t)(k4 * 4 + 0) * 64 + c0]);
        if (k4 * 4 + 1 < K) FMA16(hv1, &W[(size_t)(k4 * 4 + 1) * 64 + c0]);
        if (k4 * 4 + 2 < K) FMA16(hv2, &W[(size_t)(k4 * 4 + 2) * 64 + c0]);
        if (k4 * 4 + 3 < K) FMA16(hv3, &W[(size_t)(k4 * 4 + 3) * 64 + c0]);
    }

    size_t ob = (size_t)node * 128 + half * 64 + c0;
    float4 r0 = {acc0  + bb[c0 + 0],  acc1  + bb[c0 + 1],
                 acc2  + bb[c0 + 2],  acc3  + bb[c0 + 3]};
    float4 r1 = {acc4  + bb[c0 + 4],  acc5  + bb[c0 + 5],
                 acc6  + bb[c0 + 6],  acc7  + bb[c0 + 7]};
    float4 r2 = {acc8  + bb[c0 + 8],  acc9  + bb[c0 + 9],
                 acc10 + bb[c0 + 10], acc11 + bb[c0 + 11]};
    float4 r3 = {acc12 + bb[c0 + 12], acc13 + bb[c0 + 13],
                 acc14 + bb[c0 + 14], acc15 + bb[c0 + 15]};
    *(float4*)&xcat[ob + 0]  = r0;
    *(float4*)&xcat[ob + 4]  = r1;
    *(float4*)&xcat[ob + 8]  = r2;
    *(float4*)&xcat[ob + 12] = r3;
}

// ---------------- edge phase ----------------

// 8-lane-group sum, all lanes get total. VALU-pipe DPP, no DS shuffles.
__device__ __forceinline__ float red8(float x) {
    x += __int_as_float(__builtin_amdgcn_update_dpp(
            0, __float_as_int(x), 0xB1, 0xF, 0xF, true));   // quad xor1
    x += __int_as_float(__builtin_amdgcn_update_dpp(
            0, __float_as_int(x), 0x4E, 0xF, 0xF, true));   // quad xor2
    x += __int_as_float(__builtin_amdgcn_update_dpp(
            0, __float_as_int(x), 0x141, 0xF, 0xF, true));  // row_half_mirror
    return x;
}

__device__ __forceinline__ float pe_of(const float* __restrict__ xl_s, int sl,
                                       int oc, float4 xra, float4 xrb,
                                       float4 ata, float4 atb,
                                       float4& va, float4& vb) {
    va = *(const float4*)&xl_s[sl * XSTR + oc * 8];
    vb = *(const float4*)&xl_s[sl * XSTR + oc * 8 + 4];
    float t, d;
    t = va.x + xra.x; d  = fmaxf(t, 0.2f * t) * ata.x;
    t = va.y + xra.y; d += fmaxf(t, 0.2f * t) * ata.y;
    t = va.z + xra.z; d += fmaxf(t, 0.2f * t) * ata.z;
    t = va.w + xra.w; d += fmaxf(t, 0.2f * t) * ata.w;
    t = vb.x + xrb.x; d += fmaxf(t, 0.2f * t) * atb.x;
    t = vb.y + xrb.y; d += fmaxf(t, 0.2f * t) * atb.y;
    t = vb.z + xrb.z; d += fmaxf(t, 0.2f * t) * atb.z;
    t = vb.w + xrb.w; d += fmaxf(t, 0.2f * t) * atb.w;
    return red8(d);
}

template<int RELU, int FINAL>
__global__ __launch_bounds__(EBLK)
void k_edge(const float* __restrict__ xcat, const unsigned short* __restrict__ csr,
            const int* __restrict__ off, const float* __restrict__ att,
            const float* __restrict__ bias, const int* __restrict__ reach,
            float* __restrict__ out) {
    __shared__ __align__(16) float xl_s[NPG * XSTR];
    __shared__ __align__(8) unsigned short csr_s[CSTR];
    __shared__ unsigned short off_s[404];
    int g = blockIdx.x;
    int gbase = g * NPG;
    int tid = threadIdx.x;

    for (int q = tid; q < NPG * 16; q += EBLK) {            // xl half, 6400 f4
        int node = q >> 4, c4 = q & 15;
        *(float4*)&xl_s[node * XSTR + c4 * 4] =
            *(const float4*)&xcat[(size_t)(gbase + node) * 128 + c4 * 4];
    }
    const unsigned int* csrg = (const unsigned int*)(csr + (size_t)g * CSTR);
    for (int q = tid; q < CSTR / 2; q += EBLK)
        ((unsigned int*)csr_s)[q] = csrg[q];
    for (int q = tid; q < NPG + 1; q += EBLK)
        off_s[q] = (unsigned short)(off[gbase + q] - g * CSTR);
    __syncthreads();

    int grp = tid >> 3;                                     // 128 groups
    int oc  = tid & 7;                                      // channel octant
    float4 ata = *(const float4*)&att[oc * 8];
    float4 atb = *(const float4*)&att[oc * 8 + 4];
    float4 bia = *(const float4*)&bias[oc * 8];
    float4 bib = *(const float4*)&bias[oc * 8 + 4];

    for (int dl = grp; dl < NPG; dl += EBLK / 8) {
        int node = gbase + dl;
        float4 xra = *(const float4*)&xcat[(size_t)node * 128 + 64 + oc * 8];
        float4 xrb = *(const float4*)&xcat[(size_t)node * 128 + 64 + oc * 8 + 4];
        int beg = off_s[dl], end = off_s[dl + 1];

        float4 aa, ab, va, vb;
        float m = pe_of(xl_s, dl, oc, xra, xrb, ata, atb, va, vb); // self loop
        float dsum = 1.f;
        aa = va; ab = vb;

        int p = beg + 1;
        int pa = (p + 3) & ~3;                 // first 4-aligned slot
        if (pa > end) pa = end;
        for (; p < pa; ++p) {                  // prologue (0..3 edges)
            float4 wa, wb;
            float pe = pe_of(xl_s, csr_s[p], oc, xra, xrb, ata, atb, wa, wb);
            float cm = fmaxf(m, pe);
            float sc = __expf(m - cm);
            float ex = __expf(pe - cm);
            m = cm;
            dsum = dsum * sc + ex;
            aa.x = aa.x * sc + ex * wa.x;  aa.y = aa.y * sc + ex * wa.y;
            aa.z = aa.z * sc + ex * wa.z;  aa.w = aa.w * sc + ex * wa.w;
            ab.x = ab.x * sc + ex * wb.x;  ab.y = ab.y * sc + ex * wb.y;
            ab.z = ab.z * sc + ex * wb.z;  ab.w = ab.w * sc + ex * wb.w;
        }
        for (; p + 4 <= end; p += 4) {         // aligned 4-edge chunks
            unsigned long long iv = *(const unsigned long long*)&csr_s[p];
            int s0 = (int)(iv & 0xFFFF),         s1 = (int)((iv >> 16) & 0xFFFF);
            int s2 = (int)((iv >> 32) & 0xFFFF), s3 = (int)(iv >> 48);
            float4 v0a, v0b, v1a, v1b, v2a, v2b, v3a, v3b;
            float p0 = pe_of(xl_s, s0, oc, xra, xrb, ata, atb, v0a, v0b);
            float p1 = pe_of(xl_s, s1, oc, xra, xrb, ata, atb, v1a, v1b);
            float p2 = pe_of(xl_s, s2, oc, xra, xrb, ata, atb, v2a, v2b);
            float p3 = pe_of(xl_s, s3, oc, xra, xrb, ata, atb, v3a, v3b);
            float cm = fmaxf(fmaxf(fmaxf(p0, p1), fmaxf(p2, p3)), m);
            float sc = __expf(m - cm);          // == 1.0 usually
            m = cm;
            float e0 = __expf(p0 - m), e1 = __expf(p1 - m);
            float e2 = __expf(p2 - m), e3 = __expf(p3 - m);
            dsum = dsum * sc + (e0 + e1) + (e2 + e3);
            aa.x = aa.x * sc + e0 * v0a.x + e1 * v1a.x + e2 * v2a.x + e3 * v3a.x;
            aa.y = aa.y * sc + e0 * v0a.y + e1 * v1a.y + e2 * v2a.y + e3 * v3a.y;
            aa.z = aa.z * sc + e0 * v0a.z + e1 * v1a.z + e2 * v2a.z + e3 * v3a.z;
            aa.w = aa.w * sc + e0 * v0a.w + e1 * v1a.w + e2 * v2a.w + e3 * v3a.w;
            ab.x = ab.x * sc + e0 * v0b.x + e1 * v1b.x + e2 * v2b.x + e3 * v3b.x;
            ab.y = ab.y * sc + e0 * v0b.y + e1 * v1b.y + e2 * v2b.y + e3 * v3b.y;
            ab.z = ab.z * sc + e0 * v0b.z + e1 * v1b.z + e2 * v2b.z + e3 * v3b.z;
            ab.w = ab.w * sc + e0 * v0b.w + e1 * v1b.w + e2 * v2b.w + e3 * v3b.w;
        }
        for (; p < end; ++p) {                 // tail (0..3 edges)
            float4 wa, wb;
            float pe = pe_of(xl_s, csr_s[p], oc, xra, xrb, ata, atb, wa, wb);
            float cm = fmaxf(m, pe);
            float sc = __expf(m - cm);
            float ex = __expf(pe - cm);
            m = cm;
            dsum = dsum * sc + ex;
            aa.x = aa.x * sc + ex * wa.x;  aa.y = aa.y * sc + ex * wa.y;
            aa.z = aa.z * sc + ex * wa.z;  aa.w = aa.w * sc + ex * wa.w;
            ab.x = ab.x * sc + ex * wb.x;  ab.y = ab.y * sc + ex * wb.y;
            ab.z = ab.z * sc + ex * wb.z;  ab.w = ab.w * sc + ex * wb.w;
        }

        float inv = 1.0f / dsum;
        float4 ra = {aa.x * inv + bia.x, aa.y * inv + bia.y,
                     aa.z * inv + bia.z, aa.w * inv + bia.w};
        float4 rb = {ab.x * inv + bib.x, ab.y * inv + bib.y,
                     ab.z * inv + bib.z, ab.w * inv + bib.w};
        if (RELU) {
            ra.x = fmaxf(ra.x, 0.f); ra.y = fmaxf(ra.y, 0.f);
            ra.z = fmaxf(ra.z, 0.f); ra.w = fmaxf(ra.w, 0.f);
            rb.x = fmaxf(rb.x, 0.f); rb.y = fmaxf(rb.y, 0.f);
            rb.z = fmaxf(rb.z, 0.f); rb.w = fmaxf(rb.w, 0.f);
        }
        if (FINAL) {                           // 67-stride rows: scalar stores
            size_t b = (size_t)node * 67 + oc * 8;
            out[b + 0] = ra.x; out[b + 1] = ra.y;
            out[b + 2] = ra.z; out[b + 3] = ra.w;
            out[b + 4] = rb.x; out[b + 5] = rb.y;
            out[b + 6] = rb.z; out[b + 7] = rb.w;
        } else {
            *(float4*)&out[(size_t)node * 64 + oc * 8]     = ra;
            *(float4*)&out[(size_t)node * 64 + oc * 8 + 4] = rb;
        }
    }

    if (FINAL) {                               // trailing 3 feature columns
        if (tid < NPG) {
            int node = gbase + tid;
            float dec = (float)(g & 63);
            float nn  = ((g & 63) == 0 && tid < 256) ? 400.f : 0.f;
            size_t b = (size_t)node * 67;
            out[b + 64] = dec;
            out[b + 65] = (float)reach[node];
            out[b + 66] = nn;
        }
    }
}

// ---------------- launch ----------------

extern "C" void kernel_launch(void* const* d_in, const int* in_sizes, int n_in,
                              void* d_out, int out_size, void* d_ws, size_t ws_size,
                              hipStream_t stream) {
    const float* x     = (const float*)d_in[0];
    const int*   ei    = (const int*)d_in[1];     // int32 per harness contract
    const int*   reach = (const int*)d_in[2];
    const float* Wl0   = (const float*)d_in[3];
    const float* Wr0   = (const float*)d_in[4];
    const float* bl0   = (const float*)d_in[5];
    const float* br0   = (const float*)d_in[6];
    const float* att0  = (const float*)d_in[7];
    const float* bias0 = (const float*)d_in[8];
    const float* Wl    = (const float*)d_in[9];
    const float* Wr    = (const float*)d_in[10];
    const float* bl    = (const float*)d_in[11];
    const float* br    = (const float*)d_in[12];
    const float* att   = (const float*)d_in[13];
    const float* bias  = (const float*)d_in[14];
    float* out = (float*)d_out;

    // workspace: h (26.2 MB) | xcat (52.4 MB) | csr (3.5 MB) | off | cursor
    char* ws = (char*)d_ws;
    float* h    = (float*)ws;  ws += (size_t)N_NODES * 64 * 4;
    float* xcat = (float*)ws;  ws += (size_t)N_NODES * 128 * 4;
    unsigned short* csr = (unsigned short*)ws;  ws += (size_t)E_TOT * 2;
    int* off    = (int*)ws;    ws += (size_t)(N_NODES + 1) * 4;
    int* cursor = (int*)ws;

    k_init   <<<(N_NODES + 255) / 256, 256, 0, stream>>>(cursor, off);
    k_count  <<<(E_IN + 255) / 256, 256, 0, stream>>>(ei, cursor);
    k_scan   <<<N_GRAPH, 512, 0, stream>>>(cursor, off, csr);
    k_scatter<<<(E_IN + 255) / 256, 256, 0, stream>>>(ei, cursor, csr);

    k_transform<7><<<N_NODES / 64 * 2, 256, 0, stream>>>(
        x, Wl0, Wr0, bl0, br0, xcat);
    k_edge<1, 0><<<N_GRAPH, EBLK, 0, stream>>>(xcat, csr, off, att0, bias0,
                                               reach, h);

    for (int i = 0; i < 4; ++i) {
        k_transform<64><<<N_NODES / 64 * 2, 256, 0, stream>>>(
            h, Wl + i * 4096, Wr + i * 4096, bl + i * 64, br + i * 64, xcat);
        if (i < 3) {
            k_edge<1, 0><<<N_GRAPH, EBLK, 0, stream>>>(
                xcat, csr, off, att + i * 64, bias + i * 64, reach, h);
        } else {
            k_edge<0, 1><<<N_GRAPH, EBLK, 0, stream>>>(
                xcat, csr, off, att + i * 64, bias + i * 64, reach, out);
        }
    }
}

// Round 12
// 511.840 us; speedup vs baseline: 1.1322x; 1.0935x over previous
//
#include <hip/hip_runtime.h>

// ---------------------------------------------------------------------------
// GATv2 feature extractor, MI355X (gfx950).
// Graphs are 400-node independent blocks; edges are graph-contiguous.
//  - CSR-by-dst built on device (counts -> per-graph scan+degree-sort ->
//    scatter). Harness delivers integer inputs as int32.
//  - k_transform: lane=node, LDS-free; W via wave-uniform scalar loads.
//  - k_edge: one 1024-thr block per graph, launch_bounds(1024,4) so the
//    compiler targets the real occupancy (LDS 120KiB -> 1 block/CU) with
//    <=128 VGPR (R9: bare launch_bounds(1024) capped VGPR at 56, lost ILP).
//    8-lane groups, 8 ch/lane, DPP reduce. Dsts processed in DEGREE-SORTED
//    order so each wave's 8 groups have near-equal edge counts (R9 profile:
//    VALU-issue-bound with ~3x instruction bloat from divergent trip counts).
//    Single uniform 4-edge chunk loop with clamped indices + masked pe
//    (no prologue/tail paths).
// ---------------------------------------------------------------------------

static constexpr int N_NODES = 102400;
static constexpr int N_GRAPH = 256;
static constexpr int NPG     = 400;
static constexpr int EPG     = 6400;
static constexpr int E_IN    = 1638400;
static constexpr int CSTR    = EPG + NPG;     // 6800 CSR slots per graph
static constexpr int E_TOT   = E_IN + N_NODES;
static constexpr int XSTR    = 68;            // padded LDS row stride (floats)
static constexpr int EBLK    = 1024;          // k_edge block size (16 waves)

// ---------------- CSR build ----------------

__global__ __launch_bounds__(256)
void k_init(int* __restrict__ cursor, int* __restrict__ off) {
    int i = blockIdx.x * 256 + threadIdx.x;
    if (i < N_NODES) cursor[i] = 1;            // self-loop pre-count
    if (i == 0) off[N_NODES] = E_TOT;
}

__global__ __launch_bounds__(256)
void k_count(const int* __restrict__ ei, int* __restrict__ cursor) {
    int e = blockIdx.x * 256 + threadIdx.x;
    if (e >= E_IN) return;
    unsigned d = (unsigned)ei[E_IN + e];       // int32 input (harness contract)
    if (d < (unsigned)N_NODES) atomicAdd(&cursor[d], 1);
}

// scan + degree counting-sort (order[] = dst-local ids, ascending degree)
__global__ __launch_bounds__(512)
void k_scan(int* __restrict__ cursor, int* __restrict__ off,
            unsigned short* __restrict__ csr, unsigned short* __restrict__ order) {
    __shared__ int s[512];
    __shared__ int hist[64];
    int g = blockIdx.x, t = threadIdx.x;
    int base = g * NPG;
    int cnt = (t < NPG) ? cursor[base + t] : 0;
    s[t] = cnt;
    if (t < 64) hist[t] = 0;
    for (int d = 1; d < 512; d <<= 1) {
        __syncthreads();
        int v = (t >= d) ? s[t - d] : 0;
        __syncthreads();
        s[t] += v;
    }
    __syncthreads();
    int deg = cnt < 63 ? cnt : 63;
    if (t < NPG) atomicAdd(&hist[deg], 1);
    if (t < NPG) {
        int o = g * CSTR + (s[t] - cnt);       // exclusive prefix
        off[base + t] = o;
        cursor[base + t] = o + 1;              // slot 0 = self loop
        csr[o] = (unsigned short)t;
    }
    __syncthreads();
    if (t == 0) {                              // exclusive prefix of hist
        int acc = 0;
        for (int i = 0; i < 64; ++i) { int v = hist[i]; hist[i] = acc; acc += v; }
    }
    __syncthreads();
    if (t < NPG) {
        int pos = atomicAdd(&hist[deg], 1);
        order[base + pos] = (unsigned short)t;
    }
}

__global__ __launch_bounds__(256)
void k_scatter(const int* __restrict__ ei, int* __restrict__ cursor,
               unsigned short* __restrict__ csr) {
    int e = blockIdx.x * 256 + threadIdx.x;
    if (e >= E_IN) return;
    unsigned s = (unsigned)ei[e];
    unsigned d = (unsigned)ei[E_IN + e];
    if (d >= (unsigned)N_NODES || s >= (unsigned)N_NODES) return;  // guard
    int pos = atomicAdd(&cursor[d], 1);
    csr[pos] = (unsigned short)(s % NPG);      // src is in dst's graph
}

// ---------------- node transform (LDS-free, lane = node) ----------------

#define FMA16(hk, wp) {                                                        \
    float4 w0_ = *(const float4*)&(wp)[0];                                     \
    float4 w1_ = *(const float4*)&(wp)[4];                                     \
    float4 w2_ = *(const float4*)&(wp)[8];                                     \
    float4 w3_ = *(const float4*)&(wp)[12];                                    \
    acc0  += (hk) * w0_.x; acc1  += (hk) * w0_.y;                              \
    acc2  += (hk) * w0_.z; acc3  += (hk) * w0_.w;                              \
    acc4  += (hk) * w1_.x; acc5  += (hk) * w1_.y;                              \
    acc6  += (hk) * w1_.z; acc7  += (hk) * w1_.w;                              \
    acc8  += (hk) * w2_.x; acc9  += (hk) * w2_.y;                              \
    acc10 += (hk) * w2_.z; acc11 += (hk) * w2_.w;                              \
    acc12 += (hk) * w3_.x; acc13 += (hk) * w3_.y;                              \
    acc14 += (hk) * w3_.z; acc15 += (hk) * w3_.w; }

template<int K>
__global__ __launch_bounds__(256)
void k_transform(const float* __restrict__ h, const float* __restrict__ Wl,
                 const float* __restrict__ Wr, const float* __restrict__ bl,
                 const float* __restrict__ br, float* __restrict__ xcat) {
    int bid  = blockIdx.x;
    int half = bid & 1;
    int tid  = threadIdx.x;
    int lane = tid & 63;
    int node = (bid >> 1) * 64 + lane;
    int c0   = __builtin_amdgcn_readfirstlane((tid >> 6) * 16);
    const float* __restrict__ W  = half ? Wr : Wl;
    const float* __restrict__ bb = half ? br : bl;

    float acc0 = 0.f, acc1 = 0.f, acc2 = 0.f, acc3 = 0.f;
    float acc4 = 0.f, acc5 = 0.f, acc6 = 0.f, acc7 = 0.f;
    float acc8 = 0.f, acc9 = 0.f, acc10 = 0.f, acc11 = 0.f;
    float acc12 = 0.f, acc13 = 0.f, acc14 = 0.f, acc15 = 0.f;

    constexpr int KQ = (K + 3) / 4;
    #pragma unroll
    for (int k4 = 0; k4 < KQ; ++k4) {
        float hv0, hv1, hv2, hv3;
        if constexpr ((K & 3) == 0) {
            float4 h4 = *(const float4*)&h[(size_t)node * K + k4 * 4];
            hv0 = h4.x; hv1 = h4.y; hv2 = h4.z; hv3 = h4.w;
        } else {
            const float* hr = &h[(size_t)node * K + k4 * 4];
            hv0 = (k4 * 4 + 0 < K) ? hr[0] : 0.f;
            hv1 = (k4 * 4 + 1 < K) ? hr[1] : 0.f;
            hv2 = (k4 * 4 + 2 < K) ? hr[2] : 0.f;
            hv3 = (k4 * 4 + 3 < K) ? hr[3] : 0.f;
        }
        if (k4 * 4 + 0 < K) FMA16(hv0, &W[(size_t)(k4 * 4 + 0) * 64 + c0]);
        if (k4 * 4 + 1 < K) FMA16(hv1, &W[(size_t)(k4 * 4 + 1) * 64 + c0]);
        if (k4 * 4 + 2 < K) FMA16(hv2, &W[(size_t)(k4 * 4 + 2) * 64 + c0]);
        if (k4 * 4 + 3 < K) FMA16(hv3, &W[(size_t)(k4 * 4 + 3) * 64 + c0]);
    }

    size_t ob = (size_t)node * 128 + half * 64 + c0;
    float4 r0 = {acc0  + bb[c0 + 0],  acc1  + bb[c0 + 1],
                 acc2  + bb[c0 + 2],  acc3  + bb[c0 + 3]};
    float4 r1 = {acc4  + bb[c0 + 4],  acc5  + bb[c0 + 5],
                 acc6  + bb[c0 + 6],  acc7  + bb[c0 + 7]};
    float4 r2 = {acc8  + bb[c0 + 8],  acc9  + bb[c0 + 9],
                 acc10 + bb[c0 + 10], acc11 + bb[c0 + 11]};
    float4 r3 = {acc12 + bb[c0 + 12], acc13 + bb[c0 + 13],
                 acc14 + bb[c0 + 14], acc15 + bb[c0 + 15]};
    *(float4*)&xcat[ob + 0]  = r0;
    *(float4*)&xcat[ob + 4]  = r1;
    *(float4*)&xcat[ob + 8]  = r2;
    *(float4*)&xcat[ob + 12] = r3;
}

// ---------------- edge phase ----------------

// 8-lane-group sum, all lanes get total. VALU-pipe DPP, no DS shuffles.
__device__ __forceinline__ float red8(float x) {
    x += __int_as_float(__builtin_amdgcn_update_dpp(
            0, __float_as_int(x), 0xB1, 0xF, 0xF, true));   // quad xor1
    x += __int_as_float(__builtin_amdgcn_update_dpp(
            0, __float_as_int(x), 0x4E, 0xF, 0xF, true));   // quad xor2
    x += __int_as_float(__builtin_amdgcn_update_dpp(
            0, __float_as_int(x), 0x141, 0xF, 0xF, true));  // row_half_mirror
    return x;
}

__device__ __forceinline__ float pe_of(const float* __restrict__ xl_s, int sl,
                                       int oc, float4 xra, float4 xrb,
                                       float4 ata, float4 atb,
                                       float4& va, float4& vb) {
    va = *(const float4*)&xl_s[sl * XSTR + oc * 8];
    vb = *(const float4*)&xl_s[sl * XSTR + oc * 8 + 4];
    float t, d;
    t = va.x + xra.x; d  = fmaxf(t, 0.2f * t) * ata.x;
    t = va.y + xra.y; d += fmaxf(t, 0.2f * t) * ata.y;
    t = va.z + xra.z; d += fmaxf(t, 0.2f * t) * ata.z;
    t = va.w + xra.w; d += fmaxf(t, 0.2f * t) * ata.w;
    t = vb.x + xrb.x; d += fmaxf(t, 0.2f * t) * atb.x;
    t = vb.y + xrb.y; d += fmaxf(t, 0.2f * t) * atb.y;
    t = vb.z + xrb.z; d += fmaxf(t, 0.2f * t) * atb.z;
    t = vb.w + xrb.w; d += fmaxf(t, 0.2f * t) * atb.w;
    return red8(d);
}

template<int RELU, int FINAL>
__global__ __launch_bounds__(EBLK, 4)
void k_edge(const float* __restrict__ xcat, const unsigned short* __restrict__ csr,
            const int* __restrict__ off, const unsigned short* __restrict__ order,
            const float* __restrict__ att, const float* __restrict__ bias,
            const int* __restrict__ reach, float* __restrict__ out) {
    __shared__ __align__(16) float xl_s[NPG * XSTR];
    __shared__ __align__(8) unsigned short csr_s[CSTR];
    __shared__ unsigned short off_s[404];
    __shared__ unsigned short ord_s[400];
    int g = blockIdx.x;
    int gbase = g * NPG;
    int tid = threadIdx.x;

    for (int q = tid; q < NPG * 16; q += EBLK) {            // xl half, 6400 f4
        int node = q >> 4, c4 = q & 15;
        *(float4*)&xl_s[node * XSTR + c4 * 4] =
            *(const float4*)&xcat[(size_t)(gbase + node) * 128 + c4 * 4];
    }
    const unsigned int* csrg = (const unsigned int*)(csr + (size_t)g * CSTR);
    for (int q = tid; q < CSTR / 2; q += EBLK)
        ((unsigned int*)csr_s)[q] = csrg[q];
    for (int q = tid; q < NPG + 1; q += EBLK)
        off_s[q] = (unsigned short)(off[gbase + q] - g * CSTR);
    for (int q = tid; q < NPG; q += EBLK)
        ord_s[q] = order[gbase + q];
    __syncthreads();

    int grp = tid >> 3;                                     // 128 groups
    int oc  = tid & 7;                                      // channel octant
    float4 ata = *(const float4*)&att[oc * 8];
    float4 atb = *(const float4*)&att[oc * 8 + 4];
    float4 bia = *(const float4*)&bias[oc * 8];
    float4 bib = *(const float4*)&bias[oc * 8 + 4];

    for (int ii = grp; ii < NPG; ii += EBLK / 8) {
        int dl = ord_s[ii];                    // degree-sorted dst
        int node = gbase + dl;
        float4 xra = *(const float4*)&xcat[(size_t)node * 128 + 64 + oc * 8];
        float4 xrb = *(const float4*)&xcat[(size_t)node * 128 + 64 + oc * 8 + 4];
        int beg = off_s[dl], end = off_s[dl + 1];

        float4 aa, ab, va, vb;
        float m = pe_of(xl_s, dl, oc, xra, xrb, ata, atb, va, vb); // self loop
        float dsum = 1.f;
        aa = va; ab = vb;

        for (int p = beg + 1; p < end; p += 4) {   // uniform masked chunks
            bool k1 = p + 1 < end, k2 = p + 2 < end, k3 = p + 3 < end;
            int p1 = k1 ? p + 1 : end - 1;
            int p2 = k2 ? p + 2 : end - 1;
            int p3 = k3 ? p + 3 : end - 1;
            int s0 = csr_s[p],  s1 = csr_s[p1];
            int s2 = csr_s[p2], s3 = csr_s[p3];
            float4 v0a, v0b, v1a, v1b, v2a, v2b, v3a, v3b;
            float q0 = pe_of(xl_s, s0, oc, xra, xrb, ata, atb, v0a, v0b);
            float q1 = pe_of(xl_s, s1, oc, xra, xrb, ata, atb, v1a, v1b);
            float q2 = pe_of(xl_s, s2, oc, xra, xrb, ata, atb, v2a, v2b);
            float q3 = pe_of(xl_s, s3, oc, xra, xrb, ata, atb, v3a, v3b);
            q1 = k1 ? q1 : -1e30f;             // masked edges -> exp = 0
            q2 = k2 ? q2 : -1e30f;
            q3 = k3 ? q3 : -1e30f;
            float cm = fmaxf(fmaxf(fmaxf(q0, q1), fmaxf(q2, q3)), m);
            float sc = __expf(m - cm);          // == 1.0 usually
            m = cm;
            float e0 = __expf(q0 - m), e1 = __expf(q1 - m);
            float e2 = __expf(q2 - m), e3 = __expf(q3 - m);
            dsum = dsum * sc + (e0 + e1) + (e2 + e3);
            aa.x = aa.x * sc + e0 * v0a.x + e1 * v1a.x + e2 * v2a.x + e3 * v3a.x;
            aa.y = aa.y * sc + e0 * v0a.y + e1 * v1a.y + e2 * v2a.y + e3 * v3a.y;
            aa.z = aa.z * sc + e0 * v0a.z + e1 * v1a.z + e2 * v2a.z + e3 * v3a.z;
            aa.w = aa.w * sc + e0 * v0a.w + e1 * v1a.w + e2 * v2a.w + e3 * v3a.w;
            ab.x = ab.x * sc + e0 * v0b.x + e1 * v1b.x + e2 * v2b.x + e3 * v3b.x;
            ab.y = ab.y * sc + e0 * v0b.y + e1 * v1b.y + e2 * v2b.y + e3 * v3b.y;
            ab.z = ab.z * sc + e0 * v0b.z + e1 * v1b.z + e2 * v2b.z + e3 * v3b.z;
            ab.w = ab.w * sc + e0 * v0b.w + e1 * v1b.w + e2 * v2b.w + e3 * v3b.w;
        }

        float inv = 1.0f / dsum;
        float4 ra = {aa.x * inv + bia.x, aa.y * inv + bia.y,
                     aa.z * inv + bia.z, aa.w * inv + bia.w};
        float4 rb = {ab.x * inv + bib.x, ab.y * inv + bib.y,
                     ab.z * inv + bib.z, ab.w * inv + bib.w};
        if (RELU) {
            ra.x = fmaxf(ra.x, 0.f); ra.y = fmaxf(ra.y, 0.f);
            ra.z = fmaxf(ra.z, 0.f); ra.w = fmaxf(ra.w, 0.f);
            rb.x = fmaxf(rb.x, 0.f); rb.y = fmaxf(rb.y, 0.f);
            rb.z = fmaxf(rb.z, 0.f); rb.w = fmaxf(rb.w, 0.f);
        }
        if (FINAL) {                           // 67-stride rows: scalar stores
            size_t b = (size_t)node * 67 + oc * 8;
            out[b + 0] = ra.x; out[b + 1] = ra.y;
            out[b + 2] = ra.z; out[b + 3] = ra.w;
            out[b + 4] = rb.x; out[b + 5] = rb.y;
            out[b + 6] = rb.z; out[b + 7] = rb.w;
        } else {
            *(float4*)&out[(size_t)node * 64 + oc * 8]     = ra;
            *(float4*)&out[(size_t)node * 64 + oc * 8 + 4] = rb;
        }
    }

    if (FINAL) {                               // trailing 3 feature columns
        if (tid < NPG) {
            int node = gbase + tid;
            float dec = (float)(g & 63);
            float nn  = ((g & 63) == 0 && tid < 256) ? 400.f : 0.f;
            size_t b = (size_t)node * 67;
            out[b + 64] = dec;
            out[b + 65] = (float)reach[node];
            out[b + 66] = nn;
        }
    }
}

// ---------------- launch ----------------

extern "C" void kernel_launch(void* const* d_in, const int* in_sizes, int n_in,
                              void* d_out, int out_size, void* d_ws, size_t ws_size,
                              hipStream_t stream) {
    const float* x     = (const float*)d_in[0];
    const int*   ei    = (const int*)d_in[1];     // int32 per harness contract
    const int*   reach = (const int*)d_in[2];
    const float* Wl0   = (const float*)d_in[3];
    const float* Wr0   = (const float*)d_in[4];
    const float* bl0   = (const float*)d_in[5];
    const float* br0   = (const float*)d_in[6];
    const float* att0  = (const float*)d_in[7];
    const float* bias0 = (const float*)d_in[8];
    const float* Wl    = (const float*)d_in[9];
    const float* Wr    = (const float*)d_in[10];
    const float* bl    = (const float*)d_in[11];
    const float* br    = (const float*)d_in[12];
    const float* att   = (const float*)d_in[13];
    const float* bias  = (const float*)d_in[14];
    float* out = (float*)d_out;

    // workspace: h | xcat | csr | off | cursor | order  (~83.4 MB)
    char* ws = (char*)d_ws;
    float* h    = (float*)ws;  ws += (size_t)N_NODES * 64 * 4;
    float* xcat = (float*)ws;  ws += (size_t)N_NODES * 128 * 4;
    unsigned short* csr = (unsigned short*)ws;  ws += (size_t)E_TOT * 2;
    int* off    = (int*)ws;    ws += (size_t)(N_NODES + 1) * 4;
    int* cursor = (int*)ws;    ws += (size_t)N_NODES * 4;
    unsigned short* order = (unsigned short*)ws;

    k_init   <<<(N_NODES + 255) / 256, 256, 0, stream>>>(cursor, off);
    k_count  <<<(E_IN + 255) / 256, 256, 0, stream>>>(ei, cursor);
    k_scan   <<<N_GRAPH, 512, 0, stream>>>(cursor, off, csr, order);
    k_scatter<<<(E_IN + 255) / 256, 256, 0, stream>>>(ei, cursor, csr);

    k_transform<7><<<N_NODES / 64 * 2, 256, 0, stream>>>(
        x, Wl0, Wr0, bl0, br0, xcat);
    k_edge<1, 0><<<N_GRAPH, EBLK, 0, stream>>>(xcat, csr, off, order,
                                               att0, bias0, reach, h);

    for (int i = 0; i < 4; ++i) {
        k_transform<64><<<N_NODES / 64 * 2, 256, 0, stream>>>(
            h, Wl + i * 4096, Wr + i * 4096, bl + i * 64, br + i * 64, xcat);
        if (i < 3) {
            k_edge<1, 0><<<N_GRAPH, EBLK, 0, stream>>>(
                xcat, csr, off, order, att + i * 64, bias + i * 64, reach, h);
        } else {
            k_edge<0, 1><<<N_GRAPH, EBLK, 0, stream>>>(
                xcat, csr, off, order, att + i * 64, bias + i * 64, reach, out);
        }
    }
}